// Round 3
// baseline (241.854 us; speedup 1.0000x reference)
//
#include <hip/hip_runtime.h>
#include <math.h>

#define NN 50000
#define NE 600000
#define D 128
#define NH 3
#define CAP 64                              // max degree bucket (lambda=12, P(>=64)~1e-30)
#define EDGE_BLOCKS ((NE + 255) / 256)      // 2344
#define PACK_BLOCKS 192                     // 6144 Bpack units, 8 threads each

typedef short bf16x8 __attribute__((ext_vector_type(8)));
typedef float f32x4 __attribute__((ext_vector_type(4)));

__device__ __forceinline__ unsigned short f2b(float f) {
  unsigned int u = __float_as_uint(f);
  u += 0x7FFF + ((u >> 16) & 1);            // round-to-nearest-even
  return (unsigned short)(u >> 16);
}
__device__ __forceinline__ float blo(unsigned int u) {
  return __uint_as_float(u << 16);
}
__device__ __forceinline__ float bhi(unsigned int u) {
  return __uint_as_float(u & 0xffff0000u);
}

// ---------------------------------------------------------------------------
// pack_scatter: unchanged from round 2 (control).
//  bx <  2344                : edge scatter into 4-byte buckets (src|ew_bf16)
//  bx in [2344, 2344+192)    : Bpack nt<8 units — 8 threads/unit, LDS-reduced
//  next 3 blocks             : per-head score columns + sbuf
//  next 2 blocks             : bcomb
// ---------------------------------------------------------------------------
__global__ __launch_bounds__(256) void pack_scatter(const float* __restrict__ W_lin,
                                                    const float* __restrict__ W_heads,
                                                    const float* __restrict__ att_src,
                                                    const float* __restrict__ att_dst,
                                                    const float* __restrict__ b_lin,
                                                    const int* __restrict__ ei,
                                                    const int* __restrict__ eid,
                                                    const float* __restrict__ ddi,
                                                    const float* __restrict__ emb,
                                                    uint4* __restrict__ Bpack,
                                                    float* __restrict__ bcomb,
                                                    float* __restrict__ sbuf,
                                                    int* __restrict__ counts,
                                                    unsigned int* __restrict__ slots8) {
  const int bx = blockIdx.x;
  const int tid = threadIdx.x;
  if (bx < EDGE_BLOCKS) {
    int e = bx * 256 + tid;
    if (e < NE) {
      int src = ei[e], dst = ei[NE + e];
      int idx = atomicAdd(&counts[dst], 1);
      idx = idx < CAP ? idx : CAP - 1;   // safety clamp (statistically unreachable)
      float ew = emb[eid[e]] - ddi[e];
      slots8[dst * CAP + idx] = (unsigned int)src | ((unsigned int)f2b(ew) << 16);
    }
  } else if (bx < EDGE_BLOCKS + PACK_BLOCKS) {
    __shared__ float red[8][32][9];
    __shared__ float outv[32][8];
    const int pb = bx - EDGE_BLOCKS;
    const int u_in = tid & 31;
    const int part = tid >> 5;
    const int unit = pb * 32 + u_in;
    const int h = unit >> 11, r = unit & 2047;
    const int nt = r >> 8, s = (r >> 6) & 3, q = (r >> 4) & 3, n0 = r & 15;
    const int kbase = s * 32 + q * 8;
    const int n = nt * 16 + n0;
    const float* wl = W_lin + kbase * D;
    const float* wh = W_heads + h * D * D + n;
    float vals[8];
    #pragma unroll
    for (int j = 0; j < 8; ++j) vals[j] = 0.f;
    const int m0 = part * 16;
    #pragma unroll 4
    for (int i = 0; i < 16; ++i) {
      int m = m0 + i;
      float whv = wh[m * D];
      #pragma unroll
      for (int j = 0; j < 8; ++j) vals[j] += wl[j * D + m] * whv;
    }
    #pragma unroll
    for (int j = 0; j < 8; ++j) red[part][u_in][j] = vals[j];
    __syncthreads();
    {
      int u2 = tid >> 3, j2 = tid & 7;
      float acc = 0.f;
      #pragma unroll
      for (int p = 0; p < 8; ++p) acc += red[p][u2][j2];
      outv[u2][j2] = acc;
    }
    __syncthreads();
    if (tid < 32) {
      int unit2 = pb * 32 + tid;
      int h2 = unit2 >> 11, r2 = unit2 & 2047;
      unsigned int w[4];
      #pragma unroll
      for (int p = 0; p < 4; ++p)
        w[p] = (unsigned int)f2b(outv[tid][2 * p]) |
               ((unsigned int)f2b(outv[tid][2 * p + 1]) << 16);
      Bpack[h2 * 2304 + r2] = make_uint4(w[0], w[1], w[2], w[3]);
    }
  } else if (bx < EDGE_BLOCKS + PACK_BLOCKS + 3) {
    const int h = bx - (EDGE_BLOCKS + PACK_BLOCKS);
    __shared__ float wha_s[128], wha_d[128], scs[128], scd[128];
    {
      int m = tid & 127;
      const float* W = W_heads + h * D * D + m * D;
      const float* a = (tid < 128) ? (att_src + h * D) : (att_dst + h * D);
      float acc = 0.f;
      for (int n = 0; n < D; ++n) acc += W[n] * a[n];
      if (tid < 128) wha_s[m] = acc; else wha_d[m] = acc;
    }
    __syncthreads();
    {
      int k = tid & 127;
      const float* wl = W_lin + k * D;
      const float* wha = (tid < 128) ? wha_s : wha_d;
      float acc = 0.f;
      for (int m = 0; m < D; ++m) acc += wl[m] * wha[m];
      if (tid < 128) scs[k] = acc; else scd[k] = acc;
    }
    __syncthreads();
    if (tid < 2) {
      const float* wha = tid ? wha_d : wha_s;
      float a = 0.f;
      for (int k = 0; k < D; ++k) a += b_lin[k] * wha[k];
      sbuf[h * 2 + tid] = a;
    }
    {
      int s = (tid >> 6) & 3, q = (tid >> 4) & 3, n0 = tid & 15;
      int kbase = s * 32 + q * 8;
      float vals[8];
      #pragma unroll
      for (int j = 0; j < 8; ++j)
        vals[j] = (n0 == 0) ? scs[kbase + j] : ((n0 == 1) ? scd[kbase + j] : 0.f);
      unsigned int w[4];
      #pragma unroll
      for (int p = 0; p < 4; ++p)
        w[p] = (unsigned int)f2b(vals[2 * p]) | ((unsigned int)f2b(vals[2 * p + 1]) << 16);
      Bpack[h * 2304 + 2048 + tid] = make_uint4(w[0], w[1], w[2], w[3]);
    }
  } else {
    int t = (bx - (EDGE_BLOCKS + PACK_BLOCKS + 3)) * 256 + tid;
    if (t < NH * D) {
      int h = t / D, n = t - h * D;
      float acc = 0.f;
      for (int k = 0; k < D; ++k) acc += b_lin[k] * W_heads[h * D * D + k * D + n];
      bcomb[t] = acc;
    }
  }
}

// ---------------------------------------------------------------------------
// mfma_h3s: unchanged (control).
// ---------------------------------------------------------------------------
__global__ __launch_bounds__(256) void mfma_h3s(const float* __restrict__ x,
                                                const uint4* __restrict__ Bpack,
                                                const float* __restrict__ bcomb,
                                                const float* __restrict__ sbuf,
                                                unsigned short* __restrict__ h3,
                                                float* __restrict__ s_src4,
                                                float* __restrict__ s_dst4) {
  const int head = blockIdx.y;
  const int row0 = blockIdx.x * 64;
  const int tid = threadIdx.x;
  __shared__ __align__(16) unsigned short As[64][136];
  #pragma unroll
  for (int it = 0; it < 8; ++it) {
    int idx = tid + it * 256;
    int m = idx >> 5, k4 = idx & 31;
    int row = row0 + m;
    float4 v = make_float4(0.f, 0.f, 0.f, 0.f);
    if (row < NN) v = ((const float4*)(x + (size_t)row * D))[k4];
    uint2 pk;
    pk.x = (unsigned int)f2b(v.x) | ((unsigned int)f2b(v.y) << 16);
    pk.y = (unsigned int)f2b(v.z) | ((unsigned int)f2b(v.w) << 16);
    *((uint2*)&As[m][k4 * 4]) = pk;
  }
  __syncthreads();
  const int wv = tid >> 6;
  const int lane = tid & 63;
  const int n0 = lane & 15, q = lane >> 4;
  const int boff = q * 16 + n0;
  const bf16x8* Bp = (const bf16x8*)(Bpack + head * 2304);

  bf16x8 a4[4];
  #pragma unroll
  for (int s = 0; s < 4; ++s)
    a4[s] = *(const bf16x8*)&As[wv * 16 + n0][s * 32 + q * 8];

  f32x4 acc[9];
  #pragma unroll
  for (int nt = 0; nt < 9; ++nt) acc[nt] = (f32x4){0.f, 0.f, 0.f, 0.f};

  #pragma unroll
  for (int s = 0; s < 4; ++s) {
    #pragma unroll
    for (int nt = 0; nt < 9; ++nt) {
      bf16x8 b = Bp[(nt * 4 + s) * 64 + boff];
      acc[nt] = __builtin_amdgcn_mfma_f32_16x16x32_bf16(a4[s], b, acc[nt], 0, 0, 0);
    }
  }
  __syncthreads();   // all waves hoisted a4; As now dead -> reuse as out-tile
  const float* bc = bcomb + head * D;
  #pragma unroll
  for (int nt = 0; nt < 8; ++nt) {
    int col = nt * 16 + n0;
    float bv = bc[col];
    #pragma unroll
    for (int r = 0; r < 4; ++r)
      As[wv * 16 + q * 4 + r][col] = f2b(acc[nt][r] + bv);
  }
  // score columns: n0==0 -> s_src4, n0==1 -> s_dst4 (stride-4 layout)
  if (n0 < 2) {
    float sb = sbuf[head * 2 + n0];
    float* Sout = n0 ? s_dst4 : s_src4;
    #pragma unroll
    for (int r = 0; r < 4; ++r) {
      int row = row0 + wv * 16 + q * 4 + r;
      if (row < NN) Sout[row * 4 + head] = acc[8][r] + sb;
    }
  }
  __syncthreads();
  // coalesced write-out: 1024 uint4 (16 per row), 4 per thread
  #pragma unroll
  for (int i = 0; i < 4; ++i) {
    int idx = tid + i * 256;          // 0..1023
    int row = idx >> 4, c16 = idx & 15;
    int grow = row0 + row;
    if (grow < NN)
      *((uint4*)&h3[(size_t)grow * (NH * D) + head * D + c16 * 8]) =
          *((const uint4*)&As[row][c16 * 8]);
  }
}

// ---------------------------------------------------------------------------
// Gather v11: 256-thread blocks, 4 dsts/block (one per wave) -> lifts the
// workgroup-slot occupancy cap of the 64-thread version (64.7% observed).
// Quarter-split: 16 lanes per edge slot, 8 channels/lane via uint4 loads
// (half the load instrs), 4 edges concurrent + 2-unroll = 8 edges in flight.
// ---------------------------------------------------------------------------
__global__ __launch_bounds__(256) void gather11(const int* __restrict__ counts,
                                                const unsigned int* __restrict__ slots8,
                                                const float4* __restrict__ s_src4,
                                                const float4* __restrict__ s_dst4,
                                                const unsigned short* __restrict__ h3,
                                                const float* __restrict__ bias_heads,
                                                float* __restrict__ out) {
  const int dst = blockIdx.x * 4 + (threadIdx.x >> 6);   // NN = 12500*4 exact
  const int lane = threadIdx.x & 63;
  const int quarter = lane >> 4;         // 0..3: edge-slot group
  const int c = (lane & 15) * 8;         // channel base (8 channels per lane)
  int cnt = counts[dst];
  cnt = cnt < CAP ? cnt : CAP;
  const int beg = dst * CAP;
  const int end = beg + cnt;
  float4 sd = s_dst4[dst];
  float a0[8], a1[8], a2[8];
  #pragma unroll
  for (int j = 0; j < 8; ++j) { a0[j] = 0.f; a1[j] = 0.f; a2[j] = 0.f; }
  float d0 = 0.f, d1 = 0.f, d2 = 0.f;
  int s = beg + quarter;
  for (; s + 4 < end; s += 8) {
    unsigned int seA = slots8[s];
    unsigned int seB = slots8[s + 4];
    int srcA = seA & 0xffffu, srcB = seB & 0xffffu;
    float ewA = bhi(seA), ewB = bhi(seB);
    float4 ssA = s_src4[srcA];
    float4 ssB = s_src4[srcB];
    const unsigned short* ha = h3 + (size_t)srcA * (NH * D);
    const unsigned short* hb = h3 + (size_t)srcB * (NH * D);
    uint4 ua0 = *(const uint4*)&ha[c];
    uint4 ua1 = *(const uint4*)&ha[D + c];
    uint4 ua2 = *(const uint4*)&ha[2 * D + c];
    uint4 ub0 = *(const uint4*)&hb[c];
    uint4 ub1 = *(const uint4*)&hb[D + c];
    uint4 ub2 = *(const uint4*)&hb[2 * D + c];
    float vA0 = ssA.x + sd.x, vA1 = ssA.y + sd.y, vA2 = ssA.z + sd.z;
    float vB0 = ssB.x + sd.x, vB1 = ssB.y + sd.y, vB2 = ssB.z + sd.z;
    vA0 = vA0 > 0.f ? vA0 : 0.2f * vA0;
    vA1 = vA1 > 0.f ? vA1 : 0.2f * vA1;
    vA2 = vA2 > 0.f ? vA2 : 0.2f * vA2;
    vB0 = vB0 > 0.f ? vB0 : 0.2f * vB0;
    vB1 = vB1 > 0.f ? vB1 : 0.2f * vB1;
    vB2 = vB2 > 0.f ? vB2 : 0.2f * vB2;
    // no max-subtraction: |logit| <= ~10, exp safe in fp32; alpha identical
    float pA0 = __expf(vA0), pA1 = __expf(vA1), pA2 = __expf(vA2);
    float pB0 = __expf(vB0), pB1 = __expf(vB1), pB2 = __expf(vB2);
    float wa0 = pA0 * ewA, wa1 = pA1 * ewA, wa2 = pA2 * ewA;
    float wb0 = pB0 * ewB, wb1 = pB1 * ewB, wb2 = pB2 * ewB;
    const unsigned int* pa0 = (const unsigned int*)&ua0;
    const unsigned int* pa1 = (const unsigned int*)&ua1;
    const unsigned int* pa2 = (const unsigned int*)&ua2;
    const unsigned int* pb0 = (const unsigned int*)&ub0;
    const unsigned int* pb1 = (const unsigned int*)&ub1;
    const unsigned int* pb2 = (const unsigned int*)&ub2;
    #pragma unroll
    for (int w = 0; w < 4; ++w) {
      a0[2 * w]     += wa0 * blo(pa0[w]) + wb0 * blo(pb0[w]);
      a0[2 * w + 1] += wa0 * bhi(pa0[w]) + wb0 * bhi(pb0[w]);
      a1[2 * w]     += wa1 * blo(pa1[w]) + wb1 * blo(pb1[w]);
      a1[2 * w + 1] += wa1 * bhi(pa1[w]) + wb1 * bhi(pb1[w]);
      a2[2 * w]     += wa2 * blo(pa2[w]) + wb2 * blo(pb2[w]);
      a2[2 * w + 1] += wa2 * bhi(pa2[w]) + wb2 * bhi(pb2[w]);
    }
    d0 += pA0 + pB0;
    d1 += pA1 + pB1;
    d2 += pA2 + pB2;
  }
  if (s < end) {
    unsigned int seA = slots8[s];
    int srcA = seA & 0xffffu;
    float ewA = bhi(seA);
    float4 ssA = s_src4[srcA];
    const unsigned short* hp = h3 + (size_t)srcA * (NH * D);
    uint4 u0 = *(const uint4*)&hp[c];
    uint4 u1 = *(const uint4*)&hp[D + c];
    uint4 u2 = *(const uint4*)&hp[2 * D + c];
    float vA0 = ssA.x + sd.x, vA1 = ssA.y + sd.y, vA2 = ssA.z + sd.z;
    vA0 = vA0 > 0.f ? vA0 : 0.2f * vA0;
    vA1 = vA1 > 0.f ? vA1 : 0.2f * vA1;
    vA2 = vA2 > 0.f ? vA2 : 0.2f * vA2;
    float pA0 = __expf(vA0), pA1 = __expf(vA1), pA2 = __expf(vA2);
    float w0 = pA0 * ewA, w1 = pA1 * ewA, w2 = pA2 * ewA;
    const unsigned int* p0 = (const unsigned int*)&u0;
    const unsigned int* p1 = (const unsigned int*)&u1;
    const unsigned int* p2 = (const unsigned int*)&u2;
    #pragma unroll
    for (int w = 0; w < 4; ++w) {
      a0[2 * w]     += w0 * blo(p0[w]);
      a0[2 * w + 1] += w0 * bhi(p0[w]);
      a1[2 * w]     += w1 * blo(p1[w]);
      a1[2 * w + 1] += w1 * bhi(p1[w]);
      a2[2 * w]     += w2 * blo(p2[w]);
      a2[2 * w + 1] += w2 * bhi(p2[w]);
    }
    d0 += pA0; d1 += pA1; d2 += pA2;
  }
  // reduce across the 4 quarter-groups: xor 16 then xor 32
  #pragma unroll
  for (int j = 0; j < 8; ++j) {
    a0[j] += __shfl_xor(a0[j], 16, 64);
    a0[j] += __shfl_xor(a0[j], 32, 64);
    a1[j] += __shfl_xor(a1[j], 16, 64);
    a1[j] += __shfl_xor(a1[j], 32, 64);
    a2[j] += __shfl_xor(a2[j], 16, 64);
    a2[j] += __shfl_xor(a2[j], 32, 64);
  }
  d0 += __shfl_xor(d0, 16, 64); d0 += __shfl_xor(d0, 32, 64);
  d1 += __shfl_xor(d1, 16, 64); d1 += __shfl_xor(d1, 32, 64);
  d2 += __shfl_xor(d2, 16, 64); d2 += __shfl_xor(d2, 32, 64);
  if (quarter == 0) {
    float r0 = 1.f / fmaxf(d0, 1e-16f);
    float r1 = 1.f / fmaxf(d1, 1e-16f);
    float r2 = 1.f / fmaxf(d2, 1e-16f);
    float4 b00 = *((const float4*)&bias_heads[c]);
    float4 b01 = *((const float4*)&bias_heads[c + 4]);
    float4 b10 = *((const float4*)&bias_heads[D + c]);
    float4 b11 = *((const float4*)&bias_heads[D + c + 4]);
    float4 b20 = *((const float4*)&bias_heads[2 * D + c]);
    float4 b21 = *((const float4*)&bias_heads[2 * D + c + 4]);
    float4 o0, o1;
    o0.x = (a0[0] * r0 + a1[0] * r1 + a2[0] * r2 + b00.x + b10.x + b20.x) * (1.f / 3.f);
    o0.y = (a0[1] * r0 + a1[1] * r1 + a2[1] * r2 + b00.y + b10.y + b20.y) * (1.f / 3.f);
    o0.z = (a0[2] * r0 + a1[2] * r1 + a2[2] * r2 + b00.z + b10.z + b20.z) * (1.f / 3.f);
    o0.w = (a0[3] * r0 + a1[3] * r1 + a2[3] * r2 + b00.w + b10.w + b20.w) * (1.f / 3.f);
    o1.x = (a0[4] * r0 + a1[4] * r1 + a2[4] * r2 + b01.x + b11.x + b21.x) * (1.f / 3.f);
    o1.y = (a0[5] * r0 + a1[5] * r1 + a2[5] * r2 + b01.y + b11.y + b21.y) * (1.f / 3.f);
    o1.z = (a0[6] * r0 + a1[6] * r1 + a2[6] * r2 + b01.z + b11.z + b21.z) * (1.f / 3.f);
    o1.w = (a0[7] * r0 + a1[7] * r1 + a2[7] * r2 + b01.w + b11.w + b21.w) * (1.f / 3.f);
    *((float4*)&out[(size_t)dst * D + c]) = o0;
    *((float4*)&out[(size_t)dst * D + c + 4]) = o1;
  }
}

// ---------------------------------------------------------------------------
extern "C" void kernel_launch(void* const* d_in, const int* in_sizes, int n_in,
                              void* d_out, int out_size, void* d_ws, size_t ws_size,
                              hipStream_t stream) {
  const float* x          = (const float*)d_in[0];
  const int*   ei         = (const int*)d_in[1];
  const int*   eid        = (const int*)d_in[2];
  const float* ddi        = (const float*)d_in[3];
  const float* W_lin      = (const float*)d_in[4];
  const float* b_lin      = (const float*)d_in[5];
  const float* emb        = (const float*)d_in[6];
  const float* W_heads    = (const float*)d_in[7];
  const float* att_src    = (const float*)d_in[8];
  const float* att_dst    = (const float*)d_in[9];
  const float* bias_heads = (const float*)d_in[10];
  float* out = (float*)d_out;

  // workspace layout (16B-aligned chunks first)
  uint4*  Bpack  = (uint4*)d_ws;                               // NH*2304
  unsigned short* h3 = (unsigned short*)(Bpack + NH * 2304);   // NN*NH*D bf16 (38.4MB)
  unsigned int* slots8 = (unsigned int*)(h3 + (size_t)NN * NH * D); // NN*CAP (12.8MB)
  float*  bcomb  = (float*)(slots8 + (size_t)NN * CAP);        // NH*D
  float*  sbuf   = bcomb + NH * D;                             // 8
  float*  s_src4 = sbuf + 8;                                   // NN*4 (stride-4)
  float*  s_dst4 = s_src4 + (size_t)NN * 4;                    // NN*4
  int*    counts = (int*)(s_dst4 + (size_t)NN * 4);            // NN

  // 0. zero bucket counts
  hipMemsetAsync(counts, 0, (size_t)NN * sizeof(int), stream);
  // 1. scatter + parallel Bpack + scores + bcomb, fused (control)
  pack_scatter<<<EDGE_BLOCKS + PACK_BLOCKS + 5, 256, 0, stream>>>(
      W_lin, W_heads, att_src, att_dst, b_lin, ei, eid, ddi, emb, Bpack, bcomb,
      sbuf, counts, slots8);
  // 2. h3 + scores (MFMA) — unchanged control
  mfma_h3s<<<dim3((NN + 63) / 64, NH), 256, 0, stream>>>(x, Bpack, bcomb, sbuf,
                                                         h3, s_src4, s_dst4);
  // 3. per-dst gather v11: 4 dsts/block, uint4 loads, 8 edges in flight
  gather11<<<NN / 4, 256, 0, stream>>>(counts, slots8, (const float4*)s_src4,
                                       (const float4*)s_dst4, h3, bias_heads, out);
}

// Round 4
// 234.329 us; speedup vs baseline: 1.0321x; 1.0321x over previous
//
#include <hip/hip_runtime.h>
#include <math.h>

#define NN 50000
#define NE 600000
#define D 128
#define NH 3
#define CAP 64                              // max degree bucket (lambda=12, P(>=64)~1e-30)
#define EDGE_BLOCKS ((NE + 255) / 256)      // 2344
#define MFMA_BLOCKS ((NN + 63) / 64)        // 782

typedef short bf16x8 __attribute__((ext_vector_type(8)));
typedef float f32x4 __attribute__((ext_vector_type(4)));

__device__ __forceinline__ unsigned short f2b(float f) {
  unsigned int u = __float_as_uint(f);
  u += 0x7FFF + ((u >> 16) & 1);            // round-to-nearest-even
  return (unsigned short)(u >> 16);
}
__device__ __forceinline__ float blo(unsigned int u) {
  return __uint_as_float(u << 16);
}
__device__ __forceinline__ float bhi(unsigned int u) {
  return __uint_as_float(u & 0xffff0000u);
}
__device__ __forceinline__ float b2f(unsigned short us) {
  return __uint_as_float((unsigned int)us << 16);
}
__device__ __forceinline__ unsigned short f2h(float f) {
  _Float16 t = (_Float16)f;
  return *(unsigned short*)&t;
}
__device__ __forceinline__ float h2f(unsigned short us) {
  _Float16 t = *(_Float16*)&us;
  return (float)t;
}

// ---------------------------------------------------------------------------
// pack_scatter2: scatter (first, latency-bound, starts at t=0) + tiny prep.
//  bx < 2344      : edge scatter into 4-byte buckets (src|ew_bf16)
//  pb=bx-EB, pb<8 : repack W_lin fp32 -> Bpack bf16 (2048 units) [no GEMM!]
//  pb < 32        : repack W_heads -> Wpack3 bf16 (6144 units)
//  pb < 35        : per-head combined score columns (nt=8 tile of Bpack) + sbuf
//  pb == 35       : bcomb2 = (sum_h bias_h)/3
// counts[] zeroed by hipMemsetAsync before this kernel.
// ---------------------------------------------------------------------------
__global__ __launch_bounds__(256) void pack_scatter2(const float* __restrict__ W_lin,
                                                     const float* __restrict__ W_heads,
                                                     const float* __restrict__ att_src,
                                                     const float* __restrict__ att_dst,
                                                     const float* __restrict__ b_lin,
                                                     const float* __restrict__ bias_heads,
                                                     const int* __restrict__ ei,
                                                     const int* __restrict__ eid,
                                                     const float* __restrict__ ddi,
                                                     const float* __restrict__ emb,
                                                     uint4* __restrict__ Bpack,
                                                     uint4* __restrict__ Wpack3,
                                                     float* __restrict__ sbuf,
                                                     float* __restrict__ bcomb2,
                                                     int* __restrict__ counts,
                                                     unsigned int* __restrict__ slots8) {
  const int bx = blockIdx.x;
  const int tid = threadIdx.x;
  if (bx < EDGE_BLOCKS) {
    int e = bx * 256 + tid;
    if (e < NE) {
      int src = ei[e], dst = ei[NE + e];
      int idx = atomicAdd(&counts[dst], 1);
      idx = idx < CAP ? idx : CAP - 1;   // safety clamp (statistically unreachable)
      float ew = emb[eid[e]] - ddi[e];
      slots8[dst * CAP + idx] = (unsigned int)src | ((unsigned int)f2b(ew) << 16);
    }
    return;
  }
  const int pb = bx - EDGE_BLOCKS;
  if (pb < 8) {
    // ---- W_lin repack: unit r -> 8 bf16 of B[k][n], k=kbase+j, n=nt*16+n0 --
    int r = pb * 256 + tid;              // 0..2047
    int nt = r >> 8, s = (r >> 6) & 3, q = (r >> 4) & 3, n0 = r & 15;
    int kbase = s * 32 + q * 8;
    int n = nt * 16 + n0;
    unsigned int w[4];
    #pragma unroll
    for (int p = 0; p < 4; ++p) {
      unsigned short lo = f2b(W_lin[(kbase + 2 * p) * D + n]);
      unsigned short hi = f2b(W_lin[(kbase + 2 * p + 1) * D + n]);
      w[p] = (unsigned int)lo | ((unsigned int)hi << 16);
    }
    Bpack[r] = make_uint4(w[0], w[1], w[2], w[3]);
  } else if (pb < 32) {
    // ---- W_heads repack -> Wpack3 (3 chunks x 2048 units) ----
    int u = (pb - 8) * 256 + tid;        // 0..6143
    int h = u >> 11, r = u & 2047;
    int nt = r >> 8, s = (r >> 6) & 3, q = (r >> 4) & 3, n0 = r & 15;
    int kbase = s * 32 + q * 8;
    int n = nt * 16 + n0;
    const float* W = W_heads + (size_t)h * D * D;
    unsigned int w[4];
    #pragma unroll
    for (int p = 0; p < 4; ++p) {
      unsigned short lo = f2b(W[(kbase + 2 * p) * D + n]);
      unsigned short hi = f2b(W[(kbase + 2 * p + 1) * D + n]);
      w[p] = (unsigned int)lo | ((unsigned int)hi << 16);
    }
    Wpack3[h * 2048 + r] = make_uint4(w[0], w[1], w[2], w[3]);
  } else if (pb < 35) {
    // ---- combined score columns for head h: cols 2h (src), 2h+1 (dst) ----
    const int h = pb - 32;
    __shared__ float wha_s[128], wha_d[128], scs[128], scd[128];
    {
      int m = tid & 127;
      const float* W = W_heads + (size_t)h * D * D + m * D;
      const float* a = (tid < 128) ? (att_src + h * D) : (att_dst + h * D);
      float acc = 0.f;
      for (int n = 0; n < D; ++n) acc += W[n] * a[n];
      if (tid < 128) wha_s[m] = acc; else wha_d[m] = acc;
    }
    __syncthreads();
    {
      int k = tid & 127;
      const float* wl = W_lin + k * D;
      const float* wha = (tid < 128) ? wha_s : wha_d;
      float acc = 0.f;
      for (int m = 0; m < D; ++m) acc += wl[m] * wha[m];
      if (tid < 128) scs[k] = acc; else scd[k] = acc;
    }
    __syncthreads();
    if (tid < 2) {
      const float* wha = tid ? wha_d : wha_s;
      float a = 0.f;
      for (int k = 0; k < D; ++k) a += b_lin[k] * wha[k];
      sbuf[h * 2 + tid] = a;             // sbuf = [s0,d0,s1,d1,s2,d2]
    }
    {
      int s = (tid >> 6) & 3, q = (tid >> 4) & 3, n0 = tid & 15;
      int kbase = s * 32 + q * 8;
      bool mine = (n0 < 6) && ((n0 >> 1) == h);
      bool zero = (h == 0) && (n0 >= 6);
      if (mine || zero) {
        float vals[8];
        #pragma unroll
        for (int j = 0; j < 8; ++j)
          vals[j] = zero ? 0.f : ((n0 & 1) ? scd[kbase + j] : scs[kbase + j]);
        unsigned int w[4];
        #pragma unroll
        for (int p = 0; p < 4; ++p)
          w[p] = (unsigned int)f2b(vals[2 * p]) | ((unsigned int)f2b(vals[2 * p + 1]) << 16);
        Bpack[2048 + tid] = make_uint4(w[0], w[1], w[2], w[3]);
      }
    }
  } else {
    if (tid < D)
      bcomb2[tid] = (bias_heads[tid] + bias_heads[D + tid] + bias_heads[2 * D + tid]) * (1.f / 3.f);
  }
}

// ---------------------------------------------------------------------------
// mfma_x: ONE pass (was 3 heads): x_tilde = x@W_lin + b_lin -> bf16 [NN][128],
// plus 6 score columns (nt=8 tile) -> s_src4/s_dst4 (stride-4, head = n0>>1).
// Same proven 64-row tile / A-hoist / LDS-restage structure as mfma_h3s.
// ---------------------------------------------------------------------------
__global__ __launch_bounds__(256) void mfma_x(const float* __restrict__ x,
                                              const uint4* __restrict__ Bpack,
                                              const float* __restrict__ b_lin,
                                              const float* __restrict__ sbuf,
                                              unsigned short* __restrict__ xb,
                                              float* __restrict__ s_src4,
                                              float* __restrict__ s_dst4) {
  const int row0 = blockIdx.x * 64;
  const int tid = threadIdx.x;
  __shared__ __align__(16) unsigned short As[64][136];
  #pragma unroll
  for (int it = 0; it < 8; ++it) {
    int idx = tid + it * 256;
    int m = idx >> 5, k4 = idx & 31;
    int row = row0 + m;
    float4 v = make_float4(0.f, 0.f, 0.f, 0.f);
    if (row < NN) v = ((const float4*)(x + (size_t)row * D))[k4];
    uint2 pk;
    pk.x = (unsigned int)f2b(v.x) | ((unsigned int)f2b(v.y) << 16);
    pk.y = (unsigned int)f2b(v.z) | ((unsigned int)f2b(v.w) << 16);
    *((uint2*)&As[m][k4 * 4]) = pk;
  }
  __syncthreads();
  const int wv = tid >> 6;
  const int lane = tid & 63;
  const int n0 = lane & 15, q = lane >> 4;
  const int boff = q * 16 + n0;
  const bf16x8* Bp = (const bf16x8*)Bpack;

  bf16x8 a4[4];
  #pragma unroll
  for (int s = 0; s < 4; ++s)
    a4[s] = *(const bf16x8*)&As[wv * 16 + n0][s * 32 + q * 8];

  f32x4 acc[9];
  #pragma unroll
  for (int nt = 0; nt < 9; ++nt) acc[nt] = (f32x4){0.f, 0.f, 0.f, 0.f};

  #pragma unroll
  for (int s = 0; s < 4; ++s) {
    #pragma unroll
    for (int nt = 0; nt < 9; ++nt) {
      bf16x8 b = Bp[(nt * 4 + s) * 64 + boff];
      acc[nt] = __builtin_amdgcn_mfma_f32_16x16x32_bf16(a4[s], b, acc[nt], 0, 0, 0);
    }
  }
  __syncthreads();   // all waves hoisted a4; As now dead -> reuse as out-tile
  #pragma unroll
  for (int nt = 0; nt < 8; ++nt) {
    int col = nt * 16 + n0;
    float bv = b_lin[col];
    #pragma unroll
    for (int r = 0; r < 4; ++r)
      As[wv * 16 + q * 4 + r][col] = f2b(acc[nt][r] + bv);
  }
  // score cols: n0 even -> s_src4[row*4 + n0/2], odd -> s_dst4[row*4 + n0/2]
  if (n0 < 6) {
    float sb = sbuf[n0];
    float* Sout = (n0 & 1) ? s_dst4 : s_src4;
    #pragma unroll
    for (int r = 0; r < 4; ++r) {
      int row = row0 + wv * 16 + q * 4 + r;
      if (row < NN) Sout[row * 4 + (n0 >> 1)] = acc[8][r] + sb;
    }
  }
  __syncthreads();
  // coalesced write-out: 64 rows x 128 bf16 = 1024 uint4
  #pragma unroll
  for (int i = 0; i < 4; ++i) {
    int idx = tid + i * 256;          // 0..1023
    int row = idx >> 4, c16 = idx & 15;
    int grow = row0 + row;
    if (grow < NN)
      *((uint4*)&xb[(size_t)grow * D + c16 * 8]) = *((const uint4*)&As[row][c16 * 8]);
  }
}

// ---------------------------------------------------------------------------
// gather12: v10 structure (proven 70.7us) but gathers the SHARED x_tilde
// (256 B/edge instead of 3x256) and accumulates 3 head-weighted sums of it.
// Output: normalized acc (incl. 1/3) as fp16 [NN][384]. W_h applied later.
// ---------------------------------------------------------------------------
__global__ __launch_bounds__(64) void gather12(const int* __restrict__ counts,
                                               const unsigned int* __restrict__ slots8,
                                               const float4* __restrict__ s_src4,
                                               const float4* __restrict__ s_dst4,
                                               const unsigned short* __restrict__ xb,
                                               unsigned short* __restrict__ accb) {
  const int dst = blockIdx.x;
  const int lane = threadIdx.x;          // 0..63
  const int hf = lane >> 5;
  const int c = (lane & 31) * 4;         // channel base (4 channels per lane)
  int cnt = counts[dst];
  cnt = cnt < CAP ? cnt : CAP;
  const int beg = dst * CAP;
  const int end = beg + cnt;
  float4 sd = s_dst4[dst];
  float a0[4] = {0.f, 0.f, 0.f, 0.f};
  float a1[4] = {0.f, 0.f, 0.f, 0.f};
  float a2[4] = {0.f, 0.f, 0.f, 0.f};
  float d0 = 0.f, d1 = 0.f, d2 = 0.f;
  int s = beg + hf;
  for (; s + 2 < end; s += 4) {
    unsigned int seA = slots8[s];
    unsigned int seB = slots8[s + 2];
    int srcA = seA & 0xffffu, srcB = seB & 0xffffu;
    float ewA = bhi(seA), ewB = bhi(seB);
    float4 ssA = s_src4[srcA];
    float4 ssB = s_src4[srcB];
    uint2 ua = *(const uint2*)&xb[(size_t)srcA * D + c];
    uint2 ub = *(const uint2*)&xb[(size_t)srcB * D + c];
    float vA0 = ssA.x + sd.x, vA1 = ssA.y + sd.y, vA2 = ssA.z + sd.z;
    float vB0 = ssB.x + sd.x, vB1 = ssB.y + sd.y, vB2 = ssB.z + sd.z;
    vA0 = vA0 > 0.f ? vA0 : 0.2f * vA0;
    vA1 = vA1 > 0.f ? vA1 : 0.2f * vA1;
    vA2 = vA2 > 0.f ? vA2 : 0.2f * vA2;
    vB0 = vB0 > 0.f ? vB0 : 0.2f * vB0;
    vB1 = vB1 > 0.f ? vB1 : 0.2f * vB1;
    vB2 = vB2 > 0.f ? vB2 : 0.2f * vB2;
    // no max-subtraction: |logit| <= ~10, exp safe in fp32; alpha identical
    float pA0 = __expf(vA0), pA1 = __expf(vA1), pA2 = __expf(vA2);
    float pB0 = __expf(vB0), pB1 = __expf(vB1), pB2 = __expf(vB2);
    float wa0 = pA0 * ewA, wa1 = pA1 * ewA, wa2 = pA2 * ewA;
    float wb0 = pB0 * ewB, wb1 = pB1 * ewB, wb2 = pB2 * ewB;
    float xA[4] = {blo(ua.x), bhi(ua.x), blo(ua.y), bhi(ua.y)};
    float xB[4] = {blo(ub.x), bhi(ub.x), blo(ub.y), bhi(ub.y)};
    #pragma unroll
    for (int j = 0; j < 4; ++j) {
      a0[j] += wa0 * xA[j] + wb0 * xB[j];
      a1[j] += wa1 * xA[j] + wb1 * xB[j];
      a2[j] += wa2 * xA[j] + wb2 * xB[j];
    }
    d0 += pA0 + pB0;
    d1 += pA1 + pB1;
    d2 += pA2 + pB2;
  }
  if (s < end) {
    unsigned int seA = slots8[s];
    int srcA = seA & 0xffffu;
    float ewA = bhi(seA);
    float4 ssA = s_src4[srcA];
    uint2 ua = *(const uint2*)&xb[(size_t)srcA * D + c];
    float vA0 = ssA.x + sd.x, vA1 = ssA.y + sd.y, vA2 = ssA.z + sd.z;
    vA0 = vA0 > 0.f ? vA0 : 0.2f * vA0;
    vA1 = vA1 > 0.f ? vA1 : 0.2f * vA1;
    vA2 = vA2 > 0.f ? vA2 : 0.2f * vA2;
    float pA0 = __expf(vA0), pA1 = __expf(vA1), pA2 = __expf(vA2);
    float w0 = pA0 * ewA, w1 = pA1 * ewA, w2 = pA2 * ewA;
    float xA[4] = {blo(ua.x), bhi(ua.x), blo(ua.y), bhi(ua.y)};
    #pragma unroll
    for (int j = 0; j < 4; ++j) {
      a0[j] += w0 * xA[j];
      a1[j] += w1 * xA[j];
      a2[j] += w2 * xA[j];
    }
    d0 += pA0; d1 += pA1; d2 += pA2;
  }
  #pragma unroll
  for (int j = 0; j < 4; ++j) {
    a0[j] += __shfl_xor(a0[j], 32, 64);
    a1[j] += __shfl_xor(a1[j], 32, 64);
    a2[j] += __shfl_xor(a2[j], 32, 64);
  }
  d0 += __shfl_xor(d0, 32, 64);
  d1 += __shfl_xor(d1, 32, 64);
  d2 += __shfl_xor(d2, 32, 64);
  if (hf == 0) {
    float r0 = 1.f / (3.f * fmaxf(d0, 1e-16f));   // fold 1/NH here
    float r1 = 1.f / (3.f * fmaxf(d1, 1e-16f));
    float r2 = 1.f / (3.f * fmaxf(d2, 1e-16f));
    unsigned short* base = accb + (size_t)dst * (NH * D);
    uint2 o;
    o.x = (unsigned int)f2h(a0[0] * r0) | ((unsigned int)f2h(a0[1] * r0) << 16);
    o.y = (unsigned int)f2h(a0[2] * r0) | ((unsigned int)f2h(a0[3] * r0) << 16);
    *(uint2*)&base[c] = o;
    o.x = (unsigned int)f2h(a1[0] * r1) | ((unsigned int)f2h(a1[1] * r1) << 16);
    o.y = (unsigned int)f2h(a1[2] * r1) | ((unsigned int)f2h(a1[3] * r1) << 16);
    *(uint2*)&base[D + c] = o;
    o.x = (unsigned int)f2h(a2[0] * r2) | ((unsigned int)f2h(a2[1] * r2) << 16);
    o.y = (unsigned int)f2h(a2[2] * r2) | ((unsigned int)f2h(a2[3] * r2) << 16);
    *(uint2*)&base[2 * D + c] = o;
  }
}

// ---------------------------------------------------------------------------
// final_gemm: out = acc[NN][384] @ [W_h0;W_h1;W_h2] + bcomb2.  A staged per
// 128-chunk as hi/lo split-bf16 (two MFMA passes) for fp32-class precision.
// ---------------------------------------------------------------------------
__global__ __launch_bounds__(256) void final_gemm(const unsigned short* __restrict__ accb,
                                                  const uint4* __restrict__ Wpack3,
                                                  const float* __restrict__ bcomb2,
                                                  float* __restrict__ out) {
  const int row0 = blockIdx.x * 64;
  const int tid = threadIdx.x;
  __shared__ __align__(16) unsigned short Ah[64][136];
  __shared__ __align__(16) unsigned short Al[64][136];
  const int wv = tid >> 6;
  const int lane = tid & 63;
  const int n0 = lane & 15, q = lane >> 4;
  const int boff = q * 16 + n0;

  f32x4 o[8];
  #pragma unroll
  for (int nt = 0; nt < 8; ++nt) o[nt] = (f32x4){0.f, 0.f, 0.f, 0.f};

  for (int chunk = 0; chunk < NH; ++chunk) {
    if (chunk) __syncthreads();           // prior frag reads done before restage
    #pragma unroll
    for (int it = 0; it < 4; ++it) {
      int idx = tid + it * 256;           // 0..1023
      int m = idx >> 4, k8 = idx & 15;
      int row = row0 + m;
      uint4 u = make_uint4(0, 0, 0, 0);
      if (row < NN)
        u = *(const uint4*)&accb[(size_t)row * (NH * D) + chunk * D + k8 * 8];
      const unsigned int* pu = (const unsigned int*)&u;
      unsigned int hw[2], lw[2];
      #pragma unroll
      for (int p = 0; p < 2; ++p) {
        unsigned short hh[4], ll[4];
        #pragma unroll
        for (int e = 0; e < 2; ++e) {
          unsigned int word = pu[2 * p + e];
          float f0 = h2f((unsigned short)(word & 0xffffu));
          float f1 = h2f((unsigned short)(word >> 16));
          unsigned short h0 = f2b(f0), h1 = f2b(f1);
          hh[2 * e] = h0; hh[2 * e + 1] = h1;
          ll[2 * e] = f2b(f0 - b2f(h0));
          ll[2 * e + 1] = f2b(f1 - b2f(h1));
        }
        hw[p] = (unsigned int)hh[0] | ((unsigned int)hh[1] << 16);
        lw[p] = (unsigned int)ll[0] | ((unsigned int)ll[1] << 16);
        // second pair packs below
        hw[p] |= 0; lw[p] |= 0;
        // pack words 2,3 of this 8-half group
        if (true) {
          // store two 4-byte words per p (4 halves)
          ((unsigned int*)&Ah[m][k8 * 8])[2 * p]     = (unsigned int)hh[0] | ((unsigned int)hh[1] << 16);
          ((unsigned int*)&Ah[m][k8 * 8])[2 * p + 1] = (unsigned int)hh[2] | ((unsigned int)hh[3] << 16);
          ((unsigned int*)&Al[m][k8 * 8])[2 * p]     = (unsigned int)ll[0] | ((unsigned int)ll[1] << 16);
          ((unsigned int*)&Al[m][k8 * 8])[2 * p + 1] = (unsigned int)ll[2] | ((unsigned int)ll[3] << 16);
        }
      }
    }
    __syncthreads();
    bf16x8 ah[4], al[4];
    #pragma unroll
    for (int s = 0; s < 4; ++s) {
      ah[s] = *(const bf16x8*)&Ah[wv * 16 + n0][s * 32 + q * 8];
      al[s] = *(const bf16x8*)&Al[wv * 16 + n0][s * 32 + q * 8];
    }
    const bf16x8* Bp = (const bf16x8*)(Wpack3 + chunk * 2048);
    #pragma unroll
    for (int s = 0; s < 4; ++s) {
      #pragma unroll
      for (int nt = 0; nt < 8; ++nt) {
        bf16x8 b = Bp[(nt * 4 + s) * 64 + boff];
        o[nt] = __builtin_amdgcn_mfma_f32_16x16x32_bf16(ah[s], b, o[nt], 0, 0, 0);
        o[nt] = __builtin_amdgcn_mfma_f32_16x16x32_bf16(al[s], b, o[nt], 0, 0, 0);
      }
    }
  }
  // epilogue: 16-lane groups write 64B-contiguous fp32 segments
  #pragma unroll
  for (int nt = 0; nt < 8; ++nt) {
    int col = nt * 16 + n0;
    float bv = bcomb2[col];
    #pragma unroll
    for (int r = 0; r < 4; ++r) {
      int row = row0 + wv * 16 + q * 4 + r;
      if (row < NN) out[(size_t)row * D + col] = o[nt][r] + bv;
    }
  }
}

// ---------------------------------------------------------------------------
extern "C" void kernel_launch(void* const* d_in, const int* in_sizes, int n_in,
                              void* d_out, int out_size, void* d_ws, size_t ws_size,
                              hipStream_t stream) {
  const float* x          = (const float*)d_in[0];
  const int*   ei         = (const int*)d_in[1];
  const int*   eid        = (const int*)d_in[2];
  const float* ddi        = (const float*)d_in[3];
  const float* W_lin      = (const float*)d_in[4];
  const float* b_lin      = (const float*)d_in[5];
  const float* emb        = (const float*)d_in[6];
  const float* W_heads    = (const float*)d_in[7];
  const float* att_src    = (const float*)d_in[8];
  const float* att_dst    = (const float*)d_in[9];
  const float* bias_heads = (const float*)d_in[10];
  float* out = (float*)d_out;

  // workspace layout (16B-aligned chunks first); total ~66 MB
  uint4*  Bpack  = (uint4*)d_ws;                               // 2304 (W_lin | 6 score cols)
  uint4*  Wpack3 = Bpack + 2304;                               // 3*2048 (W_heads bf16)
  unsigned short* xb = (unsigned short*)(Wpack3 + NH * 2048);  // NN*D bf16 (12.8MB)
  unsigned int* slots8 = (unsigned int*)(xb + (size_t)NN * D); // NN*CAP (12.8MB)
  unsigned short* accb = (unsigned short*)(slots8 + (size_t)NN * CAP); // NN*384 fp16 (38.4MB)
  float*  sbuf   = (float*)(accb + (size_t)NN * NH * D);       // 8
  float*  bcomb2 = sbuf + 8;                                   // 128
  float*  s_src4 = bcomb2 + 128;                               // NN*4 (stride-4)
  float*  s_dst4 = s_src4 + (size_t)NN * 4;                    // NN*4
  int*    counts = (int*)(s_dst4 + (size_t)NN * 4);            // NN

  // 0. zero bucket counts
  hipMemsetAsync(counts, 0, (size_t)NN * sizeof(int), stream);
  // 1. scatter (t=0) + W repacks + score cols + bcomb2 (no GEMM in prep now)
  pack_scatter2<<<EDGE_BLOCKS + 36, 256, 0, stream>>>(
      W_lin, W_heads, att_src, att_dst, b_lin, bias_heads, ei, eid, ddi, emb,
      Bpack, Wpack3, sbuf, bcomb2, counts, slots8);
  // 2. x_tilde (single pass, 1/3 the old mfma work) + score columns
  mfma_x<<<MFMA_BLOCKS, 256, 0, stream>>>(x, Bpack, b_lin, sbuf, xb,
                                          s_src4, s_dst4);
  // 3. per-dst gather of shared x_tilde: 256 B/edge (was 768), fp16 acc out
  gather12<<<NN, 64, 0, stream>>>(counts, slots8, (const float4*)s_src4,
                                  (const float4*)s_dst4, xb, accb);
  // 4. dense epilogue: acc @ [W_h] + bias, hi/lo split-bf16 MFMA
  final_gemm<<<MFMA_BLOCKS, 256, 0, stream>>>(accb, Wpack3, bcomb2, out);
}